// Round 1
// 105.647 us; speedup vs baseline: 1.2244x; 1.2244x over previous
//
#include <hip/hip_runtime.h>

#define BB 32
#define HH 512
#define WW 512
#define HW (HH * WW)
#define NPIX_F 8388608.0f          // 32*512*512
#define R1 16                      // output rows per block
#define NSTR (HH / R1)             // 32 stripes per image
#define NB (BB * NSTR)             // 1024 blocks (one full residency round)
#define NLOAD (R1 + 30)            // 46 input rows per stripe
#define NQ 128                     // float4 quads per row
#define QP 4                       // quad halo padding each side
#define NQP (NQ + 2 * QP)          // 136
#define VROWF (NQP * 4)            // 544 floats per V row

__device__ __forceinline__ void elemwise4(const float h0, const float h1,
                                          const float h2, const float h3,
                                          const float4 t, const float4 p,
                                          float& a_bce, float& a_w,
                                          float& a_i, float& a_u)
{
    const float hv[4] = {h0, h1, h2, h3};
    const float tv[4] = {t.x, t.y, t.z, t.w};
    const float pv[4] = {p.x, p.y, p.z, p.w};
    const float inv961 = (1.0f / 961.0f);
    #pragma unroll
    for (int j = 0; j < 4; ++j) {
        const float ap = hv[j] * inv961;
        const float w  = fmaf(5.0f, fabsf(ap - tv[j]), 1.0f);
        const float pr = pv[j];
        const float ea = __expf(-fabsf(pr));                  // exp(-|pr|)
        const float iv = __builtin_amdgcn_rcpf(1.0f + ea);
        const float pp = (pr >= 0.0f) ? iv : (1.0f - iv);     // sigmoid
        const float sp = fmaxf(pr, 0.0f) + __logf(1.0f + ea); // softplus
        a_bce += sp - pr * tv[j];
        a_w   += w;
        a_i   += pp * tv[j] * w;
        a_u   += (pp + tv[j]) * w;
    }
}

// One block = one (image, 16-row stripe). Phase 1: vertical 31-row running
// sums into LDS (fp32, never touches HBM). Phase 2: horizontal 31-sum from
// LDS + elementwise. Pred rows preloaded to registers at kernel start so
// their HBM latency hides under phase 1; targ rows for phase 2 are L1/L2-hot
// (the block just streamed them). Deterministic float4 partial per block.
__global__ __launch_bounds__(256, 4)
void fused_kernel(const float* __restrict__ pred, const float* __restrict__ targ,
                  float4* __restrict__ part)
{
    const int t    = threadIdx.x;          // 0..255
    const int lane = t & 63;
    const int w    = t >> 6;               // wave 0..3
    // XCD-bijective swizzle: each of the 8 XCDs gets 128 consecutive
    // (image,stripe) ids = 4 whole images (~4.2 MB targ ≈ its 4 MB L2),
    // so the 30-row vertical halo re-reads stay XCD-local.
    const int orig = blockIdx.x;
    const int bi   = (orig & 7) * (NB / 8) + (orig >> 3);
    const int stripe = bi & (NSTR - 1);
    const int b      = bi >> 5;
    const int r0 = stripe * R1;

    __shared__ __align__(16) float Vl[R1][VROWF];   // 34816 B -> 4 blocks/CU
    __shared__ float4 comb[4];

    const float* tb = targ + (size_t)b * HW;
    const float* pb = pred + (size_t)b * HW;

    // ---- preload pred rows for phase 2 (only cold phase-2 data) ----
    float4 tP[4][2];
    #pragma unroll
    for (int i = 0; i < 4; ++i) {
        const float4* p4 = (const float4*)(pb + (size_t)(r0 + w * 4 + i) * WW);
        tP[i][0] = p4[lane];
        tP[i][1] = p4[64 + lane];
    }

    // ---- zero the horizontal halo quads (4 each side x 16 rows) ----
    if (t < 128) {
        const int r = t >> 3, j = t & 7;
        const int q = (j < 4) ? j : (128 + j);      // pads: quads 0-3, 132-135
        *(float4*)&Vl[r][4 * q] = make_float4(0.f, 0.f, 0.f, 0.f);
    }

    // ---- phase 1: vertical 31-row running sums, cols 2t and 2t+1 ----
    const float2* t2p = (const float2*)tb;
    auto ld = [&](int k) -> float2 {
        const int yy = r0 - 15 + k;
        return (yy >= 0 && yy < HH) ? t2p[yy * (WW / 2) + t]
                                    : make_float2(0.f, 0.f);
    };
    float2 buf[8], sv[16];                   // 8-deep prefetch ring + leavers
    #pragma unroll
    for (int i = 0; i < 8; ++i) buf[i] = ld(i);
    float a0 = 0.f, a1 = 0.f;
    #pragma unroll
    for (int k = 0; k < NLOAD; ++k) {
        const float2 a = buf[k & 7];
        if (k < 16) sv[k] = a;               // rows that will exit the window
        if (k + 8 < NLOAD) buf[k & 7] = ld(k + 8);
        a0 += a.x; a1 += a.y;
        if (k >= 30) {                       // window for local row k-30 done
            *(float2*)&Vl[k - 30][4 * QP + 2 * t] = make_float2(a0, a1);
            a0 -= sv[k - 30].x; a1 -= sv[k - 30].y;
        }
    }

    // ---- phase-2 targ loads: issue before the barrier (L1/L2-hot) ----
    float4 tT[4][2];
    #pragma unroll
    for (int i = 0; i < 4; ++i) {
        const float4* t4 = (const float4*)(tb + (size_t)(r0 + w * 4 + i) * WW);
        tT[i][0] = t4[lane];
        tT[i][1] = t4[64 + lane];
    }
    __syncthreads();

    // ---- phase 2: horizontal 31-sums from LDS + elementwise ----
    float a_bce = 0.f, a_w = 0.f, a_i = 0.f, a_u = 0.f;
    #pragma unroll
    for (int i = 0; i < 4; ++i) {
        const float4* Vr = (const float4*)&Vl[w * 4 + i][0];
        #pragma unroll
        for (int hf = 0; hf < 2; ++hf) {
            const int q = hf * 64 + lane;    // real quad qq; padded idx qq+4
            const float4 L  = Vr[q];         // quad qq-4
            const float4 c1 = Vr[q + 1], c2 = Vr[q + 2], c3 = Vr[q + 3];
            const float4 c4 = Vr[q + 4], c5 = Vr[q + 5], c6 = Vr[q + 6];
            const float4 c7 = Vr[q + 7];
            const float4 U  = Vr[q + 8];     // quad qq+4
            const float F = ((((c1.x + c1.y) + (c1.z + c1.w))
                            + ((c2.x + c2.y) + (c2.z + c2.w)))
                           + (((c3.x + c3.y) + (c3.z + c3.w))
                            + ((c4.x + c4.y) + (c4.z + c4.w))))
                          + ((((c5.x + c5.y) + (c5.z + c5.w))
                            + ((c6.x + c6.y) + (c6.z + c6.w)))
                           +  ((c7.x + c7.y) + (c7.z + c7.w)));
            const float h0 = F + ((L.y + L.z) + L.w);        // cols 4qq-15..+15
            const float h1 = F + ((L.z + L.w) + U.x);
            const float h2 = F + (L.w + (U.x + U.y));
            const float h3 = F + ((U.x + U.y) + U.z);
            elemwise4(h0, h1, h2, h3, tT[i][hf], tP[i][hf],
                      a_bce, a_w, a_i, a_u);
        }
    }

    #pragma unroll
    for (int off = 32; off > 0; off >>= 1) {
        a_bce += __shfl_down(a_bce, off, 64);
        a_w   += __shfl_down(a_w,   off, 64);
        a_i   += __shfl_down(a_i,   off, 64);
        a_u   += __shfl_down(a_u,   off, 64);
    }
    if (lane == 0) comb[w] = make_float4(a_bce, a_w, a_i, a_u);
    __syncthreads();
    if (t == 0) {
        const float4 c0 = comb[0], c1 = comb[1];
        const float4 c2 = comb[2], c3 = comb[3];
        part[bi] = make_float4(c0.x + c1.x + c2.x + c3.x,
                               c0.y + c1.y + c2.y + c3.y,
                               c0.z + c1.z + c2.z + c3.z,
                               c0.w + c1.w + c2.w + c3.w);
    }
}

// ---- deterministic tree over 1024 partials, then the scalar formula ----
__global__ __launch_bounds__(1024)
void finalize3_kernel(const float4* __restrict__ part, float* __restrict__ out)
{
    const int lane = threadIdx.x & 63;
    const int w    = threadIdx.x >> 6;      // 16 waves; each handles 2 images
    __shared__ float4 sums[BB];

    #pragma unroll
    for (int s = 0; s < 2; ++s) {
        const int img = w * 2 + s;
        float4 acc = make_float4(0.f, 0.f, 0.f, 0.f);
        if (lane < NSTR) acc = part[img * NSTR + lane];   // 32 partials/image
        #pragma unroll
        for (int off = 32; off > 0; off >>= 1) {
            acc.x += __shfl_down(acc.x, off, 64);
            acc.y += __shfl_down(acc.y, off, 64);
            acc.z += __shfl_down(acc.z, off, 64);
            acc.w += __shfl_down(acc.w, off, 64);
        }
        if (lane == 0) sums[img] = acc;
    }
    __syncthreads();

    if (w == 0) {
        float bsum = (lane < BB) ? sums[lane].x : 0.f;
        #pragma unroll
        for (int off = 32; off > 0; off >>= 1) bsum += __shfl_down(bsum, off, 64);
        const float bce = __shfl(bsum, 0, 64) * (1.0f / NPIX_F);

        float val = 0.f;
        if (lane < BB) {
            const float wsum  = sums[lane].y;
            const float inter = sums[lane].z;
            const float uni   = sums[lane].w;
            const float w_bce = (wsum * bce + 1e-8f) / (wsum + 1e-8f);
            const float w_iou = 1.0f - (inter + 1.0f + 1e-8f) / (uni - inter + 1.0f + 1e-8f);
            val = w_bce + w_iou;
        }
        #pragma unroll
        for (int off = 32; off > 0; off >>= 1) val += __shfl_down(val, off, 64);
        if (lane == 0) out[0] = val * (1.0f / BB);
    }
}

extern "C" void kernel_launch(void* const* d_in, const int* in_sizes, int n_in,
                              void* d_out, int out_size, void* d_ws, size_t ws_size,
                              hipStream_t stream)
{
    (void)in_sizes; (void)n_in; (void)out_size; (void)ws_size;
    const float* pred = (const float*)d_in[0];   // y_pred
    const float* targ = (const float*)d_in[1];   // y_target
    float* out = (float*)d_out;
    float4* part = (float4*)d_ws;                // 1024 * 16 B = 16 KiB

    hipLaunchKernelGGL(fused_kernel, dim3(NB), dim3(256), 0, stream,
                       pred, targ, part);
    hipLaunchKernelGGL(finalize3_kernel, dim3(1), dim3(1024), 0, stream,
                       part, out);
}